// Round 12
// baseline (175.057 us; speedup 1.0000x reference)
//
#include <hip/hip_runtime.h>
#include <hip/hip_bf16.h>
#include <hip/hip_fp8.h>
#include <math.h>

// Problem constants (fixed by the reference)
#define NPTS 50000   // N data points
#define DIM  256     // feature dim (K of the GEMM)
#define BQ   2048    // batch of queries (M of the GEMM)
#define NPAD 50048   // N padded to multiple of 128

#define CH   64      // n-rows per chunk (16 KB fp8 per buffer): halves the
                     // per-block barrier count vs CH=32 (the ~3 kcyc/chunk
                     // reconvergence overhead was the dominant non-pipe cost)
#define NCH64 782    // NPAD/CH
#define NG   64      // n-groups; grid = 8 m-tiles x 64 = 512 = 2 blocks/CU
                     // (reverted from 96: fewer chunks/block amortized fixed
                     // costs worse, util fell — round-11 regression).
                     // 64%8==0 -> b%8 = g%8: all 8 m-tiles share one XCD.
#define LOG2E 1.4426950408889634f

// ---------- fast-path ws layout (float offsets; fp8 regions reuse the old
//            bf16 slots, which are 2x larger than needed) ----------
//  acc   [0,      2048)
//  x2h   [2048,   4096)   0.5*log2e*||x||^2
//  t     [4096,  54144)   0.5*log2e*||s||^2 - log2|w|  (+inf when w==0)
//  sgn   [54144, 104192)  label sign
//  xb8   [104192, 235264) fp8 e4m3 x   (2048*256 B)
//  cnt   [235264]         completion counter (u32) for fused finalize
//  sb8   [366336, ...)    fp8 e4m3 s   (NPAD*256 B, 0-padded)
#define WS_ACC 0
#define WS_X2  2048
#define WS_T   4096
#define WS_SGN 54144
#define WS_XB  104192
#define WS_CNT 235264
#define WS_SB  366336
#define WS_TOTAL_BYTES (6772480ull * 4ull)  // 27,089,920 B (gate unchanged)

// ---------- v1 fallback ws layout ----------
#define V1_ACC 0
#define V1_X2  2048
#define V1_S2  4096
#define V1_W   54096

typedef __bf16 bf16x8 __attribute__((ext_vector_type(8)));
typedef __bf16 bf16x4 __attribute__((ext_vector_type(4)));
typedef float  f32x4  __attribute__((ext_vector_type(4)));
typedef float  f32x16 __attribute__((ext_vector_type(16)));
typedef int    i32x4  __attribute__((ext_vector_type(4)));
typedef int    i32x8  __attribute__((ext_vector_type(8)));
typedef unsigned int u32;
typedef unsigned char u8;

__device__ __forceinline__ float fast_exp2(float v) {
#if __has_builtin(__builtin_amdgcn_exp2f)
  return __builtin_amdgcn_exp2f(v);   // raw v_exp_f32
#else
  return exp2f(v);
#endif
}

__device__ __forceinline__ float fast_log2(float v) {
#if __has_builtin(__builtin_amdgcn_logf)
  return __builtin_amdgcn_logf(v);    // raw v_log_f32 (log2)
#else
  return __log2f(v);
#endif
}

__device__ __forceinline__ void async_copy16(const void* g, void* l) {
  __builtin_amdgcn_global_load_lds(
      (const __attribute__((address_space(1))) u32*)g,
      (__attribute__((address_space(3))) u32*)l, 16, 0, 0);
}

// pack 4 floats -> 4 fp8 e4m3 bytes (k-order = byte order)
__device__ __forceinline__ u32 pack_fp8x4(float4 v) {
#if __has_builtin(__builtin_amdgcn_cvt_pk_fp8_f32)
  int pk = __builtin_amdgcn_cvt_pk_fp8_f32(v.x, v.y, 0, false);
  pk = __builtin_amdgcn_cvt_pk_fp8_f32(v.z, v.w, pk, true);
  return (u32)pk;
#else
  __hip_fp8_e4m3 a(v.x), b(v.y), c(v.z), d(v.w);
  return (u32)a.__x | ((u32)b.__x << 8) | ((u32)c.__x << 16) | ((u32)d.__x << 24);
#endif
}

// ============================================================
// FAST PATH (fp8 MX, 32x32x64 MFMA)
// ============================================================

// One wave per row: fp32->fp8 convert into ws, plus folded epilogue
// constants t = s2h - log2|w| and sign. Blocks 0..7 zero the accumulator;
// block 8 zeroes the completion counter.
__global__ __launch_bounds__(256) void svm_precvt10(
    const float* __restrict__ x, const float* __restrict__ s,
    const float* __restrict__ labels, const float* __restrict__ lambdas,
    float* __restrict__ ws) {
  const int wid  = blockIdx.x * 4 + (threadIdx.x >> 6);
  const int lane = threadIdx.x & 63;
  u8* xb8 = (u8*)(ws + WS_XB);
  u8* sb8 = (u8*)(ws + WS_SB);

  if (blockIdx.x < 8) ws[WS_ACC + blockIdx.x * 256 + threadIdx.x] = 0.0f;
  if (blockIdx.x == 8 && threadIdx.x == 0) *(u32*)(ws + WS_CNT) = 0u;

  if (wid < NPAD) {
    float4 v = make_float4(0.f, 0.f, 0.f, 0.f);
    if (wid < NPTS)
      v = reinterpret_cast<const float4*>(s + (size_t)wid * DIM)[lane];
    ((u32*)(sb8 + (size_t)wid * DIM))[lane] = pack_fp8x4(v);
    float ss = v.x * v.x + v.y * v.y + v.z * v.z + v.w * v.w;
    #pragma unroll
    for (int off = 32; off > 0; off >>= 1) ss += __shfl_xor(ss, off);
    if (lane == 0) {
      float s2h = 0.5f * LOG2E * ss;
      float lam = (wid < NPTS) ? lambdas[wid] : 0.0f;
      float lab = (wid < NPTS) ? labels[wid] : 1.0f;
      float mag = lam > 0.0f ? lam : 0.0f;
      ws[WS_T + wid]   = (mag > 0.0f) ? s2h - fast_log2(mag) : __builtin_inff();
      ws[WS_SGN + wid] = lab;
    }
  } else if (wid < NPAD + BQ) {
    int r = wid - NPAD;
    float4 v = reinterpret_cast<const float4*>(x + (size_t)r * DIM)[lane];
    ((u32*)(xb8 + (size_t)r * DIM))[lane] = pack_fp8x4(v);
    float ss = v.x * v.x + v.y * v.y + v.z * v.z + v.w * v.w;
    #pragma unroll
    for (int off = 32; off > 0; off >>= 1) ss += __shfl_xor(ss, off);
    if (lane == 0) ws[WS_X2 + r] = 0.5f * LOG2E * ss;
  }
}

// main22 = main20 (verified 54.9 us: fp8 e4m3, mfma_scale 32x32x64, ring-3
// counted-vmcnt schedule, NG=64, no setprio) with two deltas:
//  (a) CH=64: 16 KB chunks -> 12 barriers/block instead of 24. The ledger
//      showed ~3 kcyc/chunk of barrier-reconvergence + latency exposure on
//      top of 2.4 kcyc of pipe work; same total pipe work, half the fixed
//      cost. acc grows to 4x f32x16 (regs ~190 < 256 cap; fp8 freed afr).
//  (b) fused finalize: per-thread threadfence -> syncthreads -> one
//      device-scope counter atomic; last of 512 blocks reads acc via
//      atomicAdd(p,0.0f) (coherent read) and writes tanh(out). Removes one
//      kernel launch + graph gap per iteration.
__global__ __launch_bounds__(256, 2) void svm_main22(
    float* __restrict__ ws, const float* __restrict__ bias,
    float* __restrict__ out) {
  __shared__ u8 sB[3][16384];  // 3 x 16 KB ring, [kt4][row64 x 64B swizzled]
  __shared__ bool isLast;

  const u8* xb8 = (const u8*)(ws + WS_XB);
  const u8* sb8 = (const u8*)(ws + WS_SB);
  const float* x2g = ws + WS_X2;
  const float* tg  = ws + WS_T;
  const float* sgg = ws + WS_SGN;
  float* accOut    = ws + WS_ACC;

  const int t    = threadIdx.x;
  const int wave = t >> 6;            // 0..3
  const int lane = t & 63;
  const int l32  = lane & 31;
  const int hk   = lane >> 5;         // k-half selector
  const int g    = blockIdx.x & (NG - 1);  // n-group 0..63 (pow2: exact)
  const int mt   = blockIdx.x >> 6;        // m-tile 0..7 (256 rows each)
  const int m0   = mt * 256;
  const int c0   = (NCH64 * g) / NG;
  const int c1   = (NCH64 * (g + 1)) / NG;  // ~12 chunks per group

  // Stage chunk cc into buf: 4 gll per wave (16 x 1KB per block).
  // gll p = wave*4+i: kt = p>>2, h = p&3; lane writes phys slot h*64+lane
  // of kt's 256-slot plane. Write r = h*16+(lane>>2), q = (lane&3)^((r>>1)&3)
  // inverts phys = (r<<2|q) ^ ((r>>1)&3)  [hand-verified identity].
#define STAGE22(buf, cc)                                                      \
  do {                                                                        \
    _Pragma("unroll")                                                         \
    for (int i = 0; i < 4; ++i) {                                             \
      int p  = wave * 4 + i;             /* 0..15 */                          \
      int kt = p >> 2;                   /* 0..3  */                          \
      int h  = p & 3;                                                         \
      int r  = h * 16 + (lane >> 2);     /* 0..63 */                          \
      int q  = (lane & 3) ^ ((r >> 1) & 3);                                   \
      const u8* src = sb8 + (size_t)((cc) * CH + r) * DIM + kt * 64 + q * 16; \
      async_copy16(src, &sB[(buf)][kt * 4096 + h * 1024 + lane * 16]);        \
    }                                                                         \
  } while (0)

  // Prologue: stage c0 and c0+1 (c1-c0 >= 12).
  STAGE22(0, c0);
  STAGE22(1, c0 + 1);

  // A fragments: 2 mi x 4 kt x 32 B = 64 VGPR, loaded once, pinned opaque.
  i32x8 afr[2][4];
  #pragma unroll
  for (int mi = 0; mi < 2; ++mi)
    #pragma unroll
    for (int kt = 0; kt < 4; ++kt) {
      const u8* ap = xb8 + (size_t)(m0 + wave * 64 + mi * 32 + l32) * DIM
                         + kt * 64 + hk * 32;
      i32x4 a0 = *reinterpret_cast<const i32x4*>(ap);
      i32x4 a1 = *reinterpret_cast<const i32x4*>(ap + 16);
      afr[mi][kt] = __builtin_shufflevector(a0, a1, 0, 1, 2, 3, 4, 5, 6, 7);
    }
  #pragma unroll
  for (int mi = 0; mi < 2; ++mi)
    #pragma unroll
    for (int kt = 0; kt < 4; ++kt)
      asm volatile("" : "+v"(afr[mi][kt]));  // no remat, stays in VGPRs

  float runAcc0[16], runAcc1[16];
  #pragma unroll
  for (int i = 0; i < 16; ++i) { runAcc0[i] = 0.0f; runAcc1[i] = 0.0f; }

  // Prologue wait: all stage glls retired (afr tail may fly; their first
  // use waits them). Once per block — over-sync is negligible here.
  asm volatile("s_waitcnt vmcnt(4)" ::: "memory");
  __builtin_amdgcn_s_barrier();

  int cur = 0;
  for (int c = c0; c < c1; ++c) {
    // (1) Per-lane epilogue constants (cols c*64+l32 and c*64+32+l32).
    //     Consumed in the epilogue -> compiler-counted vmcnt certifies
    //     stage c+1 (older) complete while stage c+2 stays in flight.
    float tt0 = tg[c * CH + l32];
    float sg0 = sgg[c * CH + l32];
    float tt1 = tg[c * CH + 32 + l32];
    float sg1 = sgg[c * CH + 32 + l32];
    __builtin_amdgcn_sched_barrier(0);  // pin: tt/sg issued BEFORE stage c+2

    // (2) Stage chunk c+2 (ring slot cur+2; its last reader finished
    //     before the barrier that ended iteration c-1).
    {
      int c2 = c + 2;
      if (c2 < c1) {
        int b2 = cur + 2; if (b2 >= 3) b2 -= 3;
        STAGE22(b2, c2);
      }
    }

    // (3) Compute: 16 x mfma 32x32x64 fp8 (scales = 1.0 via 0x7F bytes),
    //     4 independent accumulator chains (2 mi x 2 nb) — good MFMA ILP.
    f32x16 acc00 = (f32x16)(0.0f), acc01 = (f32x16)(0.0f);
    f32x16 acc10 = (f32x16)(0.0f), acc11 = (f32x16)(0.0f);
    const u8* bufB = &sB[cur][0];
    #pragma unroll
    for (int kt = 0; kt < 4; ++kt) {
      const u8* bp = bufB + kt * 4096;
      // nb=0: rows l32; nb=1: rows 32+l32. Slot s0 and s0^1 per row.
      int r0 = l32;
      int s0 = ((r0 << 2) | (hk << 1)) ^ ((r0 >> 1) & 3);
      i32x4 lo0 = *reinterpret_cast<const i32x4*>(bp + s0 * 16);
      i32x4 hi0 = *reinterpret_cast<const i32x4*>(bp + (s0 ^ 1) * 16);
      i32x8 bfr0 = __builtin_shufflevector(lo0, hi0, 0, 1, 2, 3, 4, 5, 6, 7);
      int r1 = 32 + l32;
      int s1 = ((r1 << 2) | (hk << 1)) ^ ((r1 >> 1) & 3);
      i32x4 lo1 = *reinterpret_cast<const i32x4*>(bp + s1 * 16);
      i32x4 hi1 = *reinterpret_cast<const i32x4*>(bp + (s1 ^ 1) * 16);
      i32x8 bfr1 = __builtin_shufflevector(lo1, hi1, 0, 1, 2, 3, 4, 5, 6, 7);
      acc00 = __builtin_amdgcn_mfma_scale_f32_32x32x64_f8f6f4(
          afr[0][kt], bfr0, acc00, 0, 0, 0, 0x7F7F7F7F, 0, 0x7F7F7F7F);
      acc01 = __builtin_amdgcn_mfma_scale_f32_32x32x64_f8f6f4(
          afr[0][kt], bfr1, acc01, 0, 0, 0, 0x7F7F7F7F, 0, 0x7F7F7F7F);
      acc10 = __builtin_amdgcn_mfma_scale_f32_32x32x64_f8f6f4(
          afr[1][kt], bfr0, acc10, 0, 0, 0, 0x7F7F7F7F, 0, 0x7F7F7F7F);
      acc11 = __builtin_amdgcn_mfma_scale_f32_32x32x64_f8f6f4(
          afr[1][kt], bfr1, acc11, 0, 0, 0, 0x7F7F7F7F, 0, 0x7F7F7F7F);
    }

    // (4) Epilogue: p += sgn * exp2(dot*log2e - t), both n-halves.
    //     Consuming tt0 here inserts the counted vmcnt (stage c+2 flying).
    #pragma unroll
    for (int reg = 0; reg < 16; ++reg) {
      float p0 = runAcc0[reg];
      p0 = __builtin_fmaf(
          sg0, fast_exp2(__builtin_fmaf(acc00[reg], LOG2E, -tt0)), p0);
      p0 = __builtin_fmaf(
          sg1, fast_exp2(__builtin_fmaf(acc01[reg], LOG2E, -tt1)), p0);
      runAcc0[reg] = p0;
      float p1 = runAcc1[reg];
      p1 = __builtin_fmaf(
          sg0, fast_exp2(__builtin_fmaf(acc10[reg], LOG2E, -tt0)), p1);
      p1 = __builtin_fmaf(
          sg1, fast_exp2(__builtin_fmaf(acc11[reg], LOG2E, -tt1)), p1);
      runAcc1[reg] = p1;
    }

    // (5) Raw barrier — no waitcnt drain (main19/20-verified schedule).
    __builtin_amdgcn_s_barrier();
    asm volatile("" ::: "memory");
    cur = (cur + 1 < 3) ? cur + 1 : 0;
  }

  // Reduce over the 32 n-columns (lanes l32); one atomic per output row.
  // row = m0 + wave*64 + mi*32 + (reg&3) + 8*(reg>>2) + 4*hk.
  #pragma unroll
  for (int reg = 0; reg < 16; ++reg) {
    float v = runAcc0[reg];
    v += __shfl_xor(v, 1);
    v += __shfl_xor(v, 2);
    v += __shfl_xor(v, 4);
    v += __shfl_xor(v, 8);
    v += __shfl_xor(v, 16);
    if (l32 == 0) {
      int row = m0 + wave * 64 + (reg & 3) + 8 * (reg >> 2) + 4 * hk;
      atomicAdd(&accOut[row], fast_exp2(-x2g[row]) * v);
    }
  }
  #pragma unroll
  for (int reg = 0; reg < 16; ++reg) {
    float v = runAcc1[reg];
    v += __shfl_xor(v, 1);
    v += __shfl_xor(v, 2);
    v += __shfl_xor(v, 4);
    v += __shfl_xor(v, 8);
    v += __shfl_xor(v, 16);
    if (l32 == 0) {
      int row = m0 + wave * 64 + 32 + (reg & 3) + 8 * (reg >> 2) + 4 * hk;
      atomicAdd(&accOut[row], fast_exp2(-x2g[row]) * v);
    }
  }

  // ---- fused finalize: last block applies bias + tanh ----
  __threadfence();           // per-thread release of the atomics above
  __syncthreads();           // all threads of this block past their fences
  if (threadIdx.x == 0) {
    u32 old = atomicAdd((u32*)(ws + WS_CNT), 1u);
    isLast = (old == (u32)(gridDim.x - 1));
  }
  __syncthreads();
  if (isLast) {
    __threadfence();         // acquire
    for (int i = threadIdx.x; i < BQ; i += 256) {
      float v = atomicAdd(&accOut[i], 0.0f);  // coherent device-scope read
      out[i] = tanhf(v + bias[0]);
    }
  }
#undef STAGE22
}

// ============================================================
// V1 FALLBACK (used only if ws_size too small)
// ============================================================

#define BK 32

__global__ __launch_bounds__(256) void svm_precompute(
    const float* __restrict__ x, const float* __restrict__ s,
    const float* __restrict__ labels, const float* __restrict__ lambdas,
    float* __restrict__ ws) {
  int wid  = blockIdx.x * 4 + (threadIdx.x >> 6);
  int lane = threadIdx.x & 63;
  const float* src;
  if (wid < NPTS)           src = s + (size_t)wid * DIM;
  else if (wid < NPTS + BQ) src = x + (size_t)(wid - NPTS) * DIM;
  else return;
  float4 v = reinterpret_cast<const float4*>(src)[lane];
  float ss = v.x * v.x + v.y * v.y + v.z * v.z + v.w * v.w;
  #pragma unroll
  for (int off = 32; off > 0; off >>= 1) ss += __shfl_xor(ss, off);
  if (lane == 0) {
    if (wid < NPTS) {
      ws[V1_S2 + wid] = ss;
      float lam = lambdas[wid];
      ws[V1_W + wid] = labels[wid] * (lam > 0.0f ? lam : 0.0f);
    } else {
      ws[V1_X2 + (wid - NPTS)] = ss;
    }
  }
}

__global__ __launch_bounds__(256) void svm_main(
    const float* __restrict__ x, const float* __restrict__ s,
    const float* __restrict__ ws) {
  __shared__ __bf16 sA[128 * BK];
  __shared__ __bf16 sB2[128 * BK];

  const int t    = threadIdx.x;
  const int wave = t >> 6;
  const int lane = t & 63;
  const int quad = lane >> 4;
  const int l16  = lane & 15;
  const int wm   = (wave & 1) * 64;
  const int wn   = (wave >> 1) * 64;
  const int bRow0 = blockIdx.y * 128;
  const int n0    = blockIdx.x * 128;

  f32x4 acc[4][4];
  #pragma unroll
  for (int i = 0; i < 4; ++i)
    #pragma unroll
    for (int j = 0; j < 4; ++j)
      acc[i][j] = (f32x4)(0.0f);

  for (int kt = 0; kt < DIM / BK; ++kt) {
    const int k0 = kt * BK;
    __syncthreads();
    #pragma unroll
    for (int i = 0; i < 4; ++i) {
      int slot = t + i * 256;
      int r  = slot >> 3;
      int c4 = slot & 7;
      float4 va = reinterpret_cast<const float4*>(
          x + (size_t)(bRow0 + r) * DIM + k0)[c4];
      bf16x4 ha = { (__bf16)va.x, (__bf16)va.y, (__bf16)va.z, (__bf16)va.w };
      *reinterpret_cast<bf16x4*>(&sA[r * BK + c4 * 4]) = ha;

      int nrow = n0 + r;
      float4 vb = make_float4(0.f, 0.f, 0.f, 0.f);
      if (nrow < NPTS)
        vb = reinterpret_cast<const float4*>(
            s + (size_t)nrow * DIM + k0)[c4];
      bf16x4 hb = { (__bf16)vb.x, (__bf16)vb.y, (__bf16)vb.z, (__bf16)vb.w };
      *reinterpret_cast<bf16x4*>(&sB2[r * BK + c4 * 4]) = hb;
    }
    __syncthreads();

    bf16x8 af[4], bfv[4];
    #pragma unroll
    for (int mi = 0; mi < 4; ++mi)
      af[mi] = *reinterpret_cast<const bf16x8*>(
          &sA[(wm + mi * 16 + l16) * BK + quad * 8]);
    #pragma unroll
    for (int ni = 0; ni < 4; ++ni)
      bfv[ni] = *reinterpret_cast<const bf16x8*>(
          &sB2[(wn + ni * 16 + l16) * BK + quad * 8]);
    #pragma unroll
    for (int mi = 0; mi < 4; ++mi)
      #pragma unroll
      for (int ni = 0; ni < 4; ++ni)
        acc[mi][ni] = __builtin_amdgcn_mfma_f32_16x16x32_bf16(
            af[mi], bfv[ni], acc[mi][ni], 0, 0, 0);
  }

  const float* x2g = ws + V1_X2;
  const float* s2g = ws + V1_S2;
  const float* wg  = ws + V1_W;
  float* accOut    = (float*)ws + V1_ACC;

  float s2v[4], wv[4];
  #pragma unroll
  for (int ni = 0; ni < 4; ++ni) {
    int n = n0 + wn + ni * 16 + l16;
    bool ok = n < NPTS;
    s2v[ni] = ok ? s2g[n] : 0.0f;
    wv[ni]  = ok ? wg[n]  : 0.0f;
  }
  #pragma unroll
  for (int mi = 0; mi < 4; ++mi) {
    const int mbase = wm + mi * 16 + quad * 4;
    #pragma unroll
    for (int reg = 0; reg < 4; ++reg) {
      float x2r = x2g[bRow0 + mbase + reg];
      float ps = 0.0f;
      #pragma unroll
      for (int ni = 0; ni < 4; ++ni) {
        float cc = acc[mi][ni][reg];
        ps += __expf(__builtin_fmaf(-0.5f, x2r + s2v[ni], cc)) * wv[ni];
      }
      ps += __shfl_xor(ps, 1);
      ps += __shfl_xor(ps, 2);
      ps += __shfl_xor(ps, 4);
      ps += __shfl_xor(ps, 8);
      if (l16 == 0) atomicAdd(&accOut[bRow0 + mbase + reg], ps);
    }
  }
}

// ============================================================

__global__ __launch_bounds__(256) void svm_finalize(
    const float* __restrict__ ws, const float* __restrict__ bias,
    float* __restrict__ out) {
  int i = blockIdx.x * 256 + threadIdx.x;
  if (i < BQ) out[i] = tanhf(ws[i] + bias[0]);  // acc at offset 0
}

extern "C" void kernel_launch(void* const* d_in, const int* in_sizes, int n_in,
                              void* d_out, int out_size, void* d_ws, size_t ws_size,
                              hipStream_t stream) {
  const float* x       = (const float*)d_in[0];  // [2048, 256]
  const float* s       = (const float*)d_in[1];  // [50000, 256]
  const float* labels  = (const float*)d_in[2];  // [50000]
  const float* lambdas = (const float*)d_in[3];  // [50000]
  const float* bias    = (const float*)d_in[4];  // [1]
  float* out = (float*)d_out;                    // [2048]
  float* ws  = (float*)d_ws;

  if (ws_size >= WS_TOTAL_BYTES) {
    // precvt10 zeroes accumulator + completion counter; main22 fuses the
    // finalize (last block applies bias+tanh) — 2 launches total.
    svm_precvt10<<<(NPAD + BQ + 3) / 4, 256, 0, stream>>>(x, s, labels, lambdas, ws);
    svm_main22<<<8 * NG, 256, 0, stream>>>(ws, bias, out);
  } else {
    hipMemsetAsync(ws, 0, BQ * sizeof(float), stream);
    svm_precompute<<<(NPTS + BQ + 3) / 4, 256, 0, stream>>>(x, s, labels, lambdas, ws);
    dim3 grid(391, BQ / 128);
    svm_main<<<grid, 256, 0, stream>>>(x, s, ws);
    svm_finalize<<<BQ / 256, 256, 0, stream>>>(ws, bias, out);
  }
}

// Round 13
// 144.948 us; speedup vs baseline: 1.2077x; 1.2077x over previous
//
#include <hip/hip_runtime.h>
#include <hip/hip_bf16.h>
#include <hip/hip_fp8.h>
#include <math.h>

// Problem constants (fixed by the reference)
#define NPTS 50000   // N data points
#define DIM  256     // feature dim (K of the GEMM)
#define BQ   2048    // batch of queries (M of the GEMM)
#define NPAD 50048   // N padded to multiple of 128

#define CH   32      // n-rows per chunk (8 KB fp8 per buffer) — main20's size
#define NCH32 1564   // NPAD/CH
#define NG   64      // n-groups; grid = 8 m-tiles x 64 = 512 = 2 blocks/CU.
                     // 64%8==0 -> b%8 = g%8: all 8 m-tiles share one XCD.
#define LOG2E 1.4426950408889634f

// ---------- fast-path ws layout (float offsets; fp8 regions reuse the old
//            bf16 slots, which are 2x larger than needed) ----------
//  acc   [0,      2048)
//  x2h   [2048,   4096)   0.5*log2e*||x||^2
//  t     [4096,  54144)   0.5*log2e*||s||^2 - log2|w|  (+inf when w==0)
//  sgn   [54144, 104192)  label sign
//  xb8   [104192, ...)    fp8 e4m3 x   (2048*256 B)
//  sb8   [366336, ...)    fp8 e4m3 s   (NPAD*256 B, 0-padded)
#define WS_ACC 0
#define WS_X2  2048
#define WS_T   4096
#define WS_SGN 54144
#define WS_XB  104192
#define WS_SB  366336
#define WS_TOTAL_BYTES (6772480ull * 4ull)  // 27,089,920 B (gate unchanged)

// ---------- v1 fallback ws layout ----------
#define V1_ACC 0
#define V1_X2  2048
#define V1_S2  4096
#define V1_W   54096

typedef __bf16 bf16x8 __attribute__((ext_vector_type(8)));
typedef __bf16 bf16x4 __attribute__((ext_vector_type(4)));
typedef float  f32x4  __attribute__((ext_vector_type(4)));
typedef float  f32x16 __attribute__((ext_vector_type(16)));
typedef int    i32x4  __attribute__((ext_vector_type(4)));
typedef int    i32x8  __attribute__((ext_vector_type(8)));
typedef unsigned int u32;
typedef unsigned char u8;

__device__ __forceinline__ float fast_exp2(float v) {
#if __has_builtin(__builtin_amdgcn_exp2f)
  return __builtin_amdgcn_exp2f(v);   // raw v_exp_f32
#else
  return exp2f(v);
#endif
}

__device__ __forceinline__ float fast_log2(float v) {
#if __has_builtin(__builtin_amdgcn_logf)
  return __builtin_amdgcn_logf(v);    // raw v_log_f32 (log2)
#else
  return __log2f(v);
#endif
}

__device__ __forceinline__ void async_copy16(const void* g, void* l) {
  __builtin_amdgcn_global_load_lds(
      (const __attribute__((address_space(1))) u32*)g,
      (__attribute__((address_space(3))) u32*)l, 16, 0, 0);
}

// pack 4 floats -> 4 fp8 e4m3 bytes (k-order = byte order)
__device__ __forceinline__ u32 pack_fp8x4(float4 v) {
#if __has_builtin(__builtin_amdgcn_cvt_pk_fp8_f32)
  int pk = __builtin_amdgcn_cvt_pk_fp8_f32(v.x, v.y, 0, false);
  pk = __builtin_amdgcn_cvt_pk_fp8_f32(v.z, v.w, pk, true);
  return (u32)pk;
#else
  __hip_fp8_e4m3 a(v.x), b(v.y), c(v.z), d(v.w);
  return (u32)a.__x | ((u32)b.__x << 8) | ((u32)c.__x << 16) | ((u32)d.__x << 24);
#endif
}

// ============================================================
// FAST PATH (fp8 MX, 32x32x64 MFMA)
// ============================================================

// One wave per row: fp32->fp8 convert into ws, plus folded epilogue
// constants t = s2h - log2|w| and sign. Blocks 0..7 zero the accumulator.
__global__ __launch_bounds__(256) void svm_precvt10(
    const float* __restrict__ x, const float* __restrict__ s,
    const float* __restrict__ labels, const float* __restrict__ lambdas,
    float* __restrict__ ws) {
  const int wid  = blockIdx.x * 4 + (threadIdx.x >> 6);
  const int lane = threadIdx.x & 63;
  u8* xb8 = (u8*)(ws + WS_XB);
  u8* sb8 = (u8*)(ws + WS_SB);

  if (blockIdx.x < 8) ws[WS_ACC + blockIdx.x * 256 + threadIdx.x] = 0.0f;

  if (wid < NPAD) {
    float4 v = make_float4(0.f, 0.f, 0.f, 0.f);
    if (wid < NPTS)
      v = reinterpret_cast<const float4*>(s + (size_t)wid * DIM)[lane];
    ((u32*)(sb8 + (size_t)wid * DIM))[lane] = pack_fp8x4(v);
    float ss = v.x * v.x + v.y * v.y + v.z * v.z + v.w * v.w;
    #pragma unroll
    for (int off = 32; off > 0; off >>= 1) ss += __shfl_xor(ss, off);
    if (lane == 0) {
      float s2h = 0.5f * LOG2E * ss;
      float lam = (wid < NPTS) ? lambdas[wid] : 0.0f;
      float lab = (wid < NPTS) ? labels[wid] : 1.0f;
      float mag = lam > 0.0f ? lam : 0.0f;
      ws[WS_T + wid]   = (mag > 0.0f) ? s2h - fast_log2(mag) : __builtin_inff();
      ws[WS_SGN + wid] = lab;
    }
  } else if (wid < NPAD + BQ) {
    int r = wid - NPAD;
    float4 v = reinterpret_cast<const float4*>(x + (size_t)r * DIM)[lane];
    ((u32*)(xb8 + (size_t)r * DIM))[lane] = pack_fp8x4(v);
    float ss = v.x * v.x + v.y * v.y + v.z * v.z + v.w * v.w;
    #pragma unroll
    for (int off = 32; off > 0; off >>= 1) ss += __shfl_xor(ss, off);
    if (lane == 0) ws[WS_X2 + r] = 0.5f * LOG2E * ss;
  }
}

// main23 = main20 (verified 54.9 us: fp8 e4m3, mfma_scale 32x32x64, CH=32,
// ring counted-vmcnt schedule, NG=64) with EXACTLY ONE delta: TWO chunks
// per barrier (ring-4, 4x8 KB LDS). Per-chunk register structure is
// byte-identical to main20 (same acc0/acc1 pair reused for each chunk of
// the pair — round-12's CH=64 doubled live accs, the confound). Barriers
// per block: 24 -> 12. Certification chain (hand-traced, main19/20
// pattern): per pair-iter, issue tt_c -> stage c+2 -> tt_{c+1} -> stage
// c+3. Epilogue-c consumes tt_c => counted vmcnt drains stage c+1 (older)
// before compute c+1; epilogue-(c+1) consumes tt_{c+1} => drains stage
// c+2 before next iter's compute c+2. One raw s_barrier per pair bounds
// drift for slot reuse (writer of slot cur+2 vs its last reader, chunk
// c-2, are separated by that barrier).
__global__ __launch_bounds__(256, 2) void svm_main23(float* __restrict__ ws) {
  __shared__ u8 sB[4][8192];  // 4 x 8 KB ring, [kt4][row32 x 64B swizzled]

  const u8* xb8 = (const u8*)(ws + WS_XB);
  const u8* sb8 = (const u8*)(ws + WS_SB);
  const float* x2g = ws + WS_X2;
  const float* tg  = ws + WS_T;
  const float* sgg = ws + WS_SGN;
  float* accOut    = ws + WS_ACC;

  const int t    = threadIdx.x;
  const int wave = t >> 6;            // 0..3
  const int lane = t & 63;
  const int l32  = lane & 31;
  const int hk   = lane >> 5;         // k-half selector
  const int g    = blockIdx.x & (NG - 1);  // n-group 0..63 (pow2: exact)
  const int mt   = blockIdx.x >> 6;        // m-tile 0..7 (256 rows each)
  const int m0   = mt * 256;
  const int c0   = (NCH32 * g) / NG;
  const int c1   = (NCH32 * (g + 1)) / NG;  // 24 or 25 chunks

  // Stage chunk cc into buf: 2 gll per wave (8 x 1KB per block).
  // Write r = h*16+(lane>>2), q = (lane&3)^((r>>1)&3) inverts the read-side
  // phys = (r<<2|q) ^ ((r>>1)&3)  [hand-verified identity, main20].
#define STAGE23(buf, cc)                                                      \
  do {                                                                        \
    _Pragma("unroll")                                                         \
    for (int i = 0; i < 2; ++i) {                                             \
      int p  = wave * 2 + i;             /* 0..7 */                           \
      int kt = p >> 1;                   /* 0..3 */                           \
      int h  = p & 1;                                                         \
      int r  = h * 16 + (lane >> 2);                                          \
      int q  = (lane & 3) ^ ((r >> 1) & 3);                                   \
      const u8* src = sb8 + (size_t)((cc) * CH + r) * DIM + kt * 64 + q * 16; \
      async_copy16(src, &sB[(buf)][kt * 2048 + h * 1024 + lane * 16]);        \
    }                                                                         \
  } while (0)

  // One chunk's compute + epilogue, byte-identical to main20's body.
#define CHUNK23(BUFIDX, CC)                                                   \
  do {                                                                        \
    f32x16 acc0 = (f32x16)(0.0f), acc1 = (f32x16)(0.0f);                      \
    const u8* bufB = &sB[(BUFIDX)][0];                                        \
    _Pragma("unroll")                                                         \
    for (int kt = 0; kt < 4; ++kt) {                                          \
      int s0 = ((l32 << 2) | (hk << 1)) ^ ((l32 >> 1) & 3);                   \
      const u8* bp = bufB + kt * 2048;                                        \
      i32x4 lo = *reinterpret_cast<const i32x4*>(bp + s0 * 16);               \
      i32x4 hi = *reinterpret_cast<const i32x4*>(bp + (s0 ^ 1) * 16);         \
      i32x8 bfr = __builtin_shufflevector(lo, hi, 0, 1, 2, 3, 4, 5, 6, 7);    \
      acc0 = __builtin_amdgcn_mfma_scale_f32_32x32x64_f8f6f4(                 \
          afr[0][kt], bfr, acc0, 0, 0, 0, 0x7F7F7F7F, 0, 0x7F7F7F7F);         \
      acc1 = __builtin_amdgcn_mfma_scale_f32_32x32x64_f8f6f4(                 \
          afr[1][kt], bfr, acc1, 0, 0, 0, 0x7F7F7F7F, 0, 0x7F7F7F7F);         \
    }                                                                         \
    _Pragma("unroll")                                                         \
    for (int reg = 0; reg < 16; ++reg)                                        \
      runAcc0[reg] = __builtin_fmaf(                                          \
          sg_##CC, fast_exp2(__builtin_fmaf(acc0[reg], LOG2E, -tt_##CC)),     \
          runAcc0[reg]);                                                      \
    _Pragma("unroll")                                                         \
    for (int reg = 0; reg < 16; ++reg)                                        \
      runAcc1[reg] = __builtin_fmaf(                                          \
          sg_##CC, fast_exp2(__builtin_fmaf(acc1[reg], LOG2E, -tt_##CC)),     \
          runAcc1[reg]);                                                      \
  } while (0)

  // Prologue: stage c0 -> slot 0, c0+1 -> slot 1 (c1-c0 >= 24).
  STAGE23(0, c0);
  STAGE23(1, c0 + 1);

  // A fragments: 2 mi x 4 kt x 32 B = 64 VGPR, loaded once, pinned opaque.
  i32x8 afr[2][4];
  #pragma unroll
  for (int mi = 0; mi < 2; ++mi)
    #pragma unroll
    for (int kt = 0; kt < 4; ++kt) {
      const u8* ap = xb8 + (size_t)(m0 + wave * 64 + mi * 32 + l32) * DIM
                         + kt * 64 + hk * 32;
      i32x4 a0 = *reinterpret_cast<const i32x4*>(ap);
      i32x4 a1 = *reinterpret_cast<const i32x4*>(ap + 16);
      afr[mi][kt] = __builtin_shufflevector(a0, a1, 0, 1, 2, 3, 4, 5, 6, 7);
    }
  #pragma unroll
  for (int mi = 0; mi < 2; ++mi)
    #pragma unroll
    for (int kt = 0; kt < 4; ++kt)
      asm volatile("" : "+v"(afr[mi][kt]));  // no remat, stays in VGPRs

  float runAcc0[16], runAcc1[16];
  #pragma unroll
  for (int i = 0; i < 16; ++i) { runAcc0[i] = 0.0f; runAcc1[i] = 0.0f; }

  // Prologue wait: both prologue stages retired (over-waits most afr loads
  // too — once per block, negligible). Then barrier.
  asm volatile("s_waitcnt vmcnt(2)" ::: "memory");
  __builtin_amdgcn_s_barrier();

  int cur = 0;   // ring slot of chunk c (pair occupies cur, cur+1)
  int c = c0;
  for (; c + 1 < c1; c += 2) {
    // tt/sg for chunk c, BEFORE stage c+2 (pin with sched_barrier): the
    // epilogue-c wait on tt_a is then counted, and certifies stage c+1.
    float tt_a = tg[c * CH + l32];
    float sg_a = sgg[c * CH + l32];
    __builtin_amdgcn_sched_barrier(0);
    if (c + 2 < c1) { int b = (cur + 2) & 3; STAGE23(b, c + 2); }

    // tt/sg for chunk c+1, AFTER stage c+2 and BEFORE stage c+3: the
    // epilogue-(c+1) wait on tt_b certifies stage c+2 for the next iter.
    float tt_b = tg[(c + 1) * CH + l32];
    float sg_b = sgg[(c + 1) * CH + l32];
    __builtin_amdgcn_sched_barrier(0);
    if (c + 3 < c1) { int b = (cur + 3) & 3; STAGE23(b, c + 3); }

    // Chunk c (buffer certified by previous iteration's epilogue-b wait).
    CHUNK23(cur, a);
    // Chunk c+1 (buffer certified by the epilogue-a wait just above).
    CHUNK23((cur + 1) & 3, b);

    // One raw barrier per PAIR — no waitcnt drain. Bounds drift so next
    // iter's stage into slots cur+2/cur+3 can't race a slow reader.
    __builtin_amdgcn_s_barrier();
    asm volatile("" ::: "memory");
    cur = (cur + 2) & 3;
  }
  if (c < c1) {  // odd tail (c1-c0 = 25)
    float tt_a = tg[c * CH + l32];
    float sg_a = sgg[c * CH + l32];
    CHUNK23(cur, a);
  }

  // Reduce over the 32 n-columns (lanes l32); one atomic per output row.
  // row = m0 + wave*64 + mi*32 + (reg&3) + 8*(reg>>2) + 4*hk.
  #pragma unroll
  for (int reg = 0; reg < 16; ++reg) {
    float v = runAcc0[reg];
    v += __shfl_xor(v, 1);
    v += __shfl_xor(v, 2);
    v += __shfl_xor(v, 4);
    v += __shfl_xor(v, 8);
    v += __shfl_xor(v, 16);
    if (l32 == 0) {
      int row = m0 + wave * 64 + (reg & 3) + 8 * (reg >> 2) + 4 * hk;
      atomicAdd(&accOut[row], fast_exp2(-x2g[row]) * v);
    }
  }
  #pragma unroll
  for (int reg = 0; reg < 16; ++reg) {
    float v = runAcc1[reg];
    v += __shfl_xor(v, 1);
    v += __shfl_xor(v, 2);
    v += __shfl_xor(v, 4);
    v += __shfl_xor(v, 8);
    v += __shfl_xor(v, 16);
    if (l32 == 0) {
      int row = m0 + wave * 64 + 32 + (reg & 3) + 8 * (reg >> 2) + 4 * hk;
      atomicAdd(&accOut[row], fast_exp2(-x2g[row]) * v);
    }
  }
#undef CHUNK23
#undef STAGE23
}

// ============================================================
// V1 FALLBACK (used only if ws_size too small)
// ============================================================

#define BK 32

__global__ __launch_bounds__(256) void svm_precompute(
    const float* __restrict__ x, const float* __restrict__ s,
    const float* __restrict__ labels, const float* __restrict__ lambdas,
    float* __restrict__ ws) {
  int wid  = blockIdx.x * 4 + (threadIdx.x >> 6);
  int lane = threadIdx.x & 63;
  const float* src;
  if (wid < NPTS)           src = s + (size_t)wid * DIM;
  else if (wid < NPTS + BQ) src = x + (size_t)(wid - NPTS) * DIM;
  else return;
  float4 v = reinterpret_cast<const float4*>(src)[lane];
  float ss = v.x * v.x + v.y * v.y + v.z * v.z + v.w * v.w;
  #pragma unroll
  for (int off = 32; off > 0; off >>= 1) ss += __shfl_xor(ss, off);
  if (lane == 0) {
    if (wid < NPTS) {
      ws[V1_S2 + wid] = ss;
      float lam = lambdas[wid];
      ws[V1_W + wid] = labels[wid] * (lam > 0.0f ? lam : 0.0f);
    } else {
      ws[V1_X2 + (wid - NPTS)] = ss;
    }
  }
}

__global__ __launch_bounds__(256) void svm_main(
    const float* __restrict__ x, const float* __restrict__ s,
    const float* __restrict__ ws) {
  __shared__ __bf16 sA[128 * BK];
  __shared__ __bf16 sB2[128 * BK];

  const int t    = threadIdx.x;
  const int wave = t >> 6;
  const int lane = t & 63;
  const int quad = lane >> 4;
  const int l16  = lane & 15;
  const int wm   = (wave & 1) * 64;
  const int wn   = (wave >> 1) * 64;
  const int bRow0 = blockIdx.y * 128;
  const int n0    = blockIdx.x * 128;

  f32x4 acc[4][4];
  #pragma unroll
  for (int i = 0; i < 4; ++i)
    #pragma unroll
    for (int j = 0; j < 4; ++j)
      acc[i][j] = (f32x4)(0.0f);

  for (int kt = 0; kt < DIM / BK; ++kt) {
    const int k0 = kt * BK;
    __syncthreads();
    #pragma unroll
    for (int i = 0; i < 4; ++i) {
      int slot = t + i * 256;
      int r  = slot >> 3;
      int c4 = slot & 7;
      float4 va = reinterpret_cast<const float4*>(
          x + (size_t)(bRow0 + r) * DIM + k0)[c4];
      bf16x4 ha = { (__bf16)va.x, (__bf16)va.y, (__bf16)va.z, (__bf16)va.w };
      *reinterpret_cast<bf16x4*>(&sA[r * BK + c4 * 4]) = ha;

      int nrow = n0 + r;
      float4 vb = make_float4(0.f, 0.f, 0.f, 0.f);
      if (nrow < NPTS)
        vb = reinterpret_cast<const float4*>(
            s + (size_t)nrow * DIM + k0)[c4];
      bf16x4 hb = { (__bf16)vb.x, (__bf16)vb.y, (__bf16)vb.z, (__bf16)vb.w };
      *reinterpret_cast<bf16x4*>(&sB2[r * BK + c4 * 4]) = hb;
    }
    __syncthreads();

    bf16x8 af[4], bfv[4];
    #pragma unroll
    for (int mi = 0; mi < 4; ++mi)
      af[mi] = *reinterpret_cast<const bf16x8*>(
          &sA[(wm + mi * 16 + l16) * BK + quad * 8]);
    #pragma unroll
    for (int ni = 0; ni < 4; ++ni)
      bfv[ni] = *reinterpret_cast<const bf16x8*>(
          &sB2[(wn + ni * 16 + l16) * BK + quad * 8]);
    #pragma unroll
    for (int mi = 0; mi < 4; ++mi)
      #pragma unroll
      for (int ni = 0; ni < 4; ++ni)
        acc[mi][ni] = __builtin_amdgcn_mfma_f32_16x16x32_bf16(
            af[mi], bfv[ni], acc[mi][ni], 0, 0, 0);
  }

  const float* x2g = ws + V1_X2;
  const float* s2g = ws + V1_S2;
  const float* wg  = ws + V1_W;
  float* accOut    = (float*)ws + V1_ACC;

  float s2v[4], wv[4];
  #pragma unroll
  for (int ni = 0; ni < 4; ++ni) {
    int n = n0 + wn + ni * 16 + l16;
    bool ok = n < NPTS;
    s2v[ni] = ok ? s2g[n] : 0.0f;
    wv[ni]  = ok ? wg[n]  : 0.0f;
  }
  #pragma unroll
  for (int mi = 0; mi < 4; ++mi) {
    const int mbase = wm + mi * 16 + quad * 4;
    #pragma unroll
    for (int reg = 0; reg < 4; ++reg) {
      float x2r = x2g[bRow0 + mbase + reg];
      float ps = 0.0f;
      #pragma unroll
      for (int ni = 0; ni < 4; ++ni) {
        float cc = acc[mi][ni][reg];
        ps += __expf(__builtin_fmaf(-0.5f, x2r + s2v[ni], cc)) * wv[ni];
      }
      ps += __shfl_xor(ps, 1);
      ps += __shfl_xor(ps, 2);
      ps += __shfl_xor(ps, 4);
      ps += __shfl_xor(ps, 8);
      if (l16 == 0) atomicAdd(&accOut[bRow0 + mbase + reg], ps);
    }
  }
}

// ============================================================

__global__ __launch_bounds__(256) void svm_finalize(
    const float* __restrict__ ws, const float* __restrict__ bias,
    float* __restrict__ out) {
  int i = blockIdx.x * 256 + threadIdx.x;
  if (i < BQ) out[i] = tanhf(ws[i] + bias[0]);  // acc at offset 0
}

extern "C" void kernel_launch(void* const* d_in, const int* in_sizes, int n_in,
                              void* d_out, int out_size, void* d_ws, size_t ws_size,
                              hipStream_t stream) {
  const float* x       = (const float*)d_in[0];  // [2048, 256]
  const float* s       = (const float*)d_in[1];  // [50000, 256]
  const float* labels  = (const float*)d_in[2];  // [50000]
  const float* lambdas = (const float*)d_in[3];  // [50000]
  const float* bias    = (const float*)d_in[4];  // [1]
  float* out = (float*)d_out;                    // [2048]
  float* ws  = (float*)d_ws;

  if (ws_size >= WS_TOTAL_BYTES) {
    // precvt10 zeroes the accumulator region itself (blocks 0..7)
    svm_precvt10<<<(NPAD + BQ + 3) / 4, 256, 0, stream>>>(x, s, labels, lambdas, ws);
    svm_main23<<<8 * NG, 256, 0, stream>>>(ws);
    svm_finalize<<<BQ / 256, 256, 0, stream>>>(ws, bias, out);
  } else {
    hipMemsetAsync(ws, 0, BQ * sizeof(float), stream);
    svm_precompute<<<(NPTS + BQ + 3) / 4, 256, 0, stream>>>(x, s, labels, lambdas, ws);
    dim3 grid(391, BQ / 128);
    svm_main<<<grid, 256, 0, stream>>>(x, s, ws);
    svm_finalize<<<BQ / 256, 256, 0, stream>>>(ws, bias, out);
  }
}